// Round 1
// baseline (496.212 us; speedup 1.0000x reference)
//
#include <hip/hip_runtime.h>
#include <hip/hip_bf16.h>
#include <cstdint>

typedef __bf16 bf16_t;
typedef __bf16 bf16x8 __attribute__((ext_vector_type(8)));
typedef float  floatx4 __attribute__((ext_vector_type(4)));

typedef const __attribute__((address_space(1))) unsigned int* gptr_t;
typedef __attribute__((address_space(3))) unsigned int* lptr_t;

static __device__ __forceinline__ void gl2lds16(const bf16_t* g, bf16_t* l) {
  __builtin_amdgcn_global_load_lds((gptr_t)g, (lptr_t)l, 16, 0, 0);
}

// ---------------------------------------------------------------------------
// NT GEMM: C[M,N] = alpha * A[M,K] * B^T (Bt stored [N,K]) + bias[n]
// bf16 inputs, fp32 accumulate. 128x128 tile, BK=32, 256 threads (4 waves),
// each wave 64x64 = 4x4 tiles of v_mfma_f32_16x16x32_bf16 (m97 structure).
// All of M,N,K must be multiples of 128/128/32 (true for every call here).
// ---------------------------------------------------------------------------
template<int OUT_BF16, int HAS_BIAS>
__global__ __launch_bounds__(256, 2)
void gemm_nt(const bf16_t* __restrict__ A, const bf16_t* __restrict__ Bt,
             void* __restrict__ Cv, const float* __restrict__ bias,
             int M, int N, int K, float alpha,
             long sA, long sB, long sC)
{
  __shared__ __align__(16) bf16_t As[128 * 32];
  __shared__ __align__(16) bf16_t Bs[128 * 32];

  const int bz = blockIdx.z;
  A  += bz * sA;
  Bt += bz * sB;

  const int n0   = blockIdx.x * 128;
  const int m0   = blockIdx.y * 128;
  const int tid  = threadIdx.x;
  const int lane = tid & 63;
  const int wave = tid >> 6;
  const int wm   = (wave >> 1) * 64;
  const int wn   = (wave & 1) * 64;
  const int lm   = lane & 15;
  const int quad = lane >> 4;

  // staging: wave w covers rows [32w, 32w+32); lane -> (row srow, 16B chunk)
  const int srow   = lane >> 2;        // 0..15
  const int schunk = (lane & 3) * 8;   // element offset (8 bf16 = 16B)

  floatx4 acc[4][4];
#pragma unroll
  for (int i = 0; i < 4; ++i)
#pragma unroll
    for (int j = 0; j < 4; ++j)
      acc[i][j] = (floatx4)(0.f);

  for (int kk = 0; kk < K; kk += 32) {
    __syncthreads();  // prev iter's ds_reads done before LDS overwrite
#pragma unroll
    for (int t = 0; t < 2; ++t) {
      const int r = wave * 32 + t * 16 + srow;
      // LDS dest == wave-uniform base + lane*16 (required by global_load_lds)
      gl2lds16(A  + (long)(m0 + r) * K + kk + schunk, &As[r * 32 + schunk]);
      gl2lds16(Bt + (long)(n0 + r) * K + kk + schunk, &Bs[r * 32 + schunk]);
    }
    __syncthreads();  // compiler drains vmcnt(0) before s_barrier

    bf16x8 af[4], bfr[4];
#pragma unroll
    for (int i = 0; i < 4; ++i)
      af[i] = *(const bf16x8*)&As[(wm + i * 16 + lm) * 32 + quad * 8];
#pragma unroll
    for (int j = 0; j < 4; ++j)
      bfr[j] = *(const bf16x8*)&Bs[(wn + j * 16 + lm) * 32 + quad * 8];
#pragma unroll
    for (int i = 0; i < 4; ++i)
#pragma unroll
      for (int j = 0; j < 4; ++j)
        acc[i][j] = __builtin_amdgcn_mfma_f32_16x16x32_bf16(af[i], bfr[j],
                                                            acc[i][j], 0, 0, 0);
  }

  // epilogue: C/D layout col = lane&15, row = quad*4 + r (measured m89/m91)
#pragma unroll
  for (int j = 0; j < 4; ++j) {
    const int cn = n0 + wn + j * 16 + lm;
    const float bv = HAS_BIAS ? bias[cn] : 0.f;
#pragma unroll
    for (int i = 0; i < 4; ++i) {
      const int rbase = m0 + wm + i * 16 + quad * 4;
#pragma unroll
      for (int r = 0; r < 4; ++r) {
        const float v = alpha * acc[i][j][r] + bv;
        const long idx = bz * sC + (long)(rbase + r) * N + cn;
        if (OUT_BF16) ((bf16_t*)Cv)[idx] = (bf16_t)v;
        else          ((float*)Cv)[idx]  = v;
      }
    }
  }
}

// ---------------------------------------------------------------------------
// Tiled transpose -> bf16 (in: rows x cols row-major; out: cols x rows)
// ---------------------------------------------------------------------------
template<typename TIN>
__global__ void transpose_to_bf16(const TIN* __restrict__ in, bf16_t* __restrict__ out,
                                  int rows, int cols, long sIn, long sOut)
{
  __shared__ float tile[32][33];
  const int bz = blockIdx.z;
  in  += bz * sIn;
  out += bz * sOut;
  const int c0 = blockIdx.x * 32;
  const int r0 = blockIdx.y * 32;
  const int tx = threadIdx.x;   // 0..31
  const int ty = threadIdx.y;   // 0..7
#pragma unroll
  for (int i = 0; i < 32; i += 8)
    tile[ty + i][tx] = (float)in[(long)(r0 + ty + i) * cols + (c0 + tx)];
  __syncthreads();
#pragma unroll
  for (int i = 0; i < 32; i += 8)
    out[(long)(c0 + ty + i) * rows + (r0 + tx)] = (bf16_t)tile[tx][ty + i];
}

__global__ void cvt_f32_to_bf16(const float* __restrict__ in, bf16_t* __restrict__ out,
                                long n)
{
  const long i = ((long)blockIdx.x * blockDim.x + threadIdx.x) * 4;
  if (i >= n) return;
  const float4 v = *(const float4*)(in + i);
  struct alignas(8) B4 { bf16_t a, b, c, d; };
  B4 o; o.a = (bf16_t)v.x; o.b = (bf16_t)v.y; o.c = (bf16_t)v.z; o.d = (bf16_t)v.w;
  *(B4*)(out + i) = o;
}

// ---------------------------------------------------------------------------
// Softmax over the q axis (axis=-2): per column k of scores[b][q][k].
// In-place bf16. Block = 32 columns x 8 q-groups, online max/sum.
// ---------------------------------------------------------------------------
__global__ __launch_bounds__(256)
void softmax_q(bf16_t* __restrict__ sc, int S)
{
  __shared__ float rm[8][32], rl[8][32];
  bf16_t* p = sc + (long)blockIdx.z * S * S + blockIdx.x * 32;
  const int tc = threadIdx.x & 31;
  const int tg = threadIdx.x >> 5;
  float m = -3.0e38f, l = 0.f;
  for (int q = tg; q < S; q += 8) {
    const float s  = (float)p[(long)q * S + tc];
    const float nm = fmaxf(m, s);
    l = l * __expf(m - nm) + __expf(s - nm);
    m = nm;
  }
  rm[tg][tc] = m; rl[tg][tc] = l;
  __syncthreads();
  if (tg == 0) {
    float M = rm[0][tc], L = rl[0][tc];
#pragma unroll
    for (int g = 1; g < 8; ++g) {
      const float m2 = rm[g][tc], l2 = rl[g][tc];
      const float nm = fmaxf(M, m2);
      L = L * __expf(M - nm) + l2 * __expf(m2 - nm);
      M = nm;
    }
    rm[0][tc] = M; rl[0][tc] = 1.f / L;
  }
  __syncthreads();
  const float M = rm[0][tc], invL = rl[0][tc];
  for (int q = tg; q < S; q += 8) {
    const float s = (float)p[(long)q * S + tc];
    p[(long)q * S + tc] = (bf16_t)(__expf(s - M) * invL);
  }
}

// ---------------------------------------------------------------------------
extern "C" void kernel_launch(void* const* d_in, const int* in_sizes, int n_in,
                              void* d_out, int out_size, void* d_ws, size_t ws_size,
                              hipStream_t stream)
{
  const int Bz = 4, S = 2048, F = 1024, DK = 1024;
  const int M = Bz * S;  // 8192 rows, batch-flattened for the projections

  const float* x  = (const float*)d_in[0];
  const float* Wq = (const float*)d_in[1];
  const float* bq = (const float*)d_in[2];
  const float* Wk = (const float*)d_in[3];
  const float* bk = (const float*)d_in[4];
  const float* Wv = (const float*)d_in[5];
  const float* bv = (const float*)d_in[6];
  const float* Wo = (const float*)d_in[7];
  const float* bo = (const float*)d_in[8];

  char* ws = (char*)d_ws;
  const size_t MB = 1ull << 20;
  // lifetime-based aliasing: Sc overlays Xb+V (both dead by then); Ctx overlays Q
  bf16_t* Xb  = (bf16_t*)(ws + 0);        // 16MB, dead after QKV gemms
  bf16_t* V   = (bf16_t*)(ws + 16 * MB);  // 16MB, dead after V-transpose
  bf16_t* Sc  = (bf16_t*)(ws + 0);        // 32MB scores/attn
  bf16_t* Q   = (bf16_t*)(ws + 32 * MB);  // 16MB, dead after scores gemm
  bf16_t* Ctx = (bf16_t*)(ws + 32 * MB);  // 16MB
  bf16_t* Kb  = (bf16_t*)(ws + 48 * MB);  // 16MB
  bf16_t* Vt  = (bf16_t*)(ws + 64 * MB);  // 16MB
  bf16_t* WqT = (bf16_t*)(ws + 80 * MB);  // 2MB each
  bf16_t* WkT = (bf16_t*)(ws + 82 * MB);
  bf16_t* WvT = (bf16_t*)(ws + 84 * MB);
  bf16_t* WoT = (bf16_t*)(ws + 86 * MB);

  // x -> bf16
  cvt_f32_to_bf16<<<(M * F) / 1024, 256, 0, stream>>>(x, Xb, (long)M * F);

  // weight transposes (fp32 -> bf16, [K_in, N] -> [N, K_in])
  dim3 tb(32, 8);
  transpose_to_bf16<float><<<dim3(DK / 32, F / 32, 1), tb, 0, stream>>>(Wq, WqT, F, DK, 0, 0);
  transpose_to_bf16<float><<<dim3(DK / 32, F / 32, 1), tb, 0, stream>>>(Wk, WkT, F, DK, 0, 0);
  transpose_to_bf16<float><<<dim3(DK / 32, F / 32, 1), tb, 0, stream>>>(Wv, WvT, F, DK, 0, 0);
  transpose_to_bf16<float><<<dim3(F / 32, DK / 32, 1), tb, 0, stream>>>(Wo, WoT, DK, F, 0, 0);

  // projections: Q/K/V = x @ W + b  (single M=8192 GEMM each)
  dim3 gp(DK / 128, M / 128, 1);
  gemm_nt<1, 1><<<gp, 256, 0, stream>>>(Xb, WqT, Q,  bq, M, DK, F, 1.f, 0, 0, 0);
  gemm_nt<1, 1><<<gp, 256, 0, stream>>>(Xb, WkT, Kb, bk, M, DK, F, 1.f, 0, 0, 0);
  gemm_nt<1, 1><<<gp, 256, 0, stream>>>(Xb, WvT, V,  bv, M, DK, F, 1.f, 0, 0, 0);

  // V[b][s][d] -> Vt[b][d][s] so the PV gemm is also NT
  transpose_to_bf16<bf16_t><<<dim3(DK / 32, S / 32, Bz), tb, 0, stream>>>(
      V, Vt, S, DK, (long)S * DK, (long)S * DK);

  // scores[b][q][k] = (Q[b] . K[b]) / sqrt(dk)   (bf16 out)
  gemm_nt<1, 0><<<dim3(S / 128, S / 128, Bz), 256, 0, stream>>>(
      Q, Kb, Sc, nullptr, S, S, DK, 0.03125f,
      (long)S * DK, (long)S * DK, (long)S * S);

  // softmax over q (axis=-2), in place
  softmax_q<<<dim3(S / 32, 1, Bz), 256, 0, stream>>>(Sc, S);

  // ctx[b][q][d] = attn[b] @ V[b]  (via Vt, NT)
  gemm_nt<1, 0><<<dim3(DK / 128, S / 128, Bz), 256, 0, stream>>>(
      Sc, Vt, Ctx, nullptr, S, DK, S, 1.f,
      (long)S * S, (long)S * DK, (long)S * DK);

  // out = ctx @ Wo + bo  (fp32 to d_out)
  gemm_nt<0, 1><<<dim3(F / 128, M / 128, 1), 256, 0, stream>>>(
      Ctx, WoT, d_out, bo, M, F, DK, 1.f, 0, 0, 0);
}

// Round 2
// 366.497 us; speedup vs baseline: 1.3539x; 1.3539x over previous
//
#include <hip/hip_runtime.h>
#include <hip/hip_bf16.h>
#include <cstdint>

typedef __bf16 bf16_t;
typedef __bf16 bf16x8 __attribute__((ext_vector_type(8)));
typedef float  floatx4 __attribute__((ext_vector_type(4)));

typedef const __attribute__((address_space(1))) unsigned int* gptr_t;
typedef __attribute__((address_space(3))) unsigned int* lptr_t;

static __device__ __forceinline__ void gl2lds16(const bf16_t* g, bf16_t* l) {
  __builtin_amdgcn_global_load_lds((gptr_t)g, (lptr_t)l, 16, 0, 0);
}

// ---------------------------------------------------------------------------
// NT GEMM: C[M,N] = f(alpha * A[M,K] * B^T) + bias[n], f = exp if APPLY_EXP.
// bf16 inputs, fp32 accumulate. 128x128 tile, BK=32, 256 threads (4 waves),
// each wave 64x64 = 4x4 tiles of v_mfma_f32_16x16x32_bf16 (m97 structure).
// ---------------------------------------------------------------------------
template<int OUT_BF16, int HAS_BIAS, int APPLY_EXP>
__global__ __launch_bounds__(256, 2)
void gemm_nt(const bf16_t* __restrict__ A, const bf16_t* __restrict__ Bt,
             void* __restrict__ Cv, const float* __restrict__ bias,
             int M, int N, int K, float alpha,
             long sA, long sB, long sC)
{
  __shared__ __align__(16) bf16_t As[128 * 32];
  __shared__ __align__(16) bf16_t Bs[128 * 32];

  const int bz = blockIdx.z;
  A  += bz * sA;
  Bt += bz * sB;

  const int n0   = blockIdx.x * 128;
  const int m0   = blockIdx.y * 128;
  const int tid  = threadIdx.x;
  const int lane = tid & 63;
  const int wave = tid >> 6;
  const int wm   = (wave >> 1) * 64;
  const int wn   = (wave & 1) * 64;
  const int lm   = lane & 15;
  const int quad = lane >> 4;

  const int srow   = lane >> 2;        // 0..15
  const int schunk = (lane & 3) * 8;   // element offset (8 bf16 = 16B)

  floatx4 acc[4][4];
#pragma unroll
  for (int i = 0; i < 4; ++i)
#pragma unroll
    for (int j = 0; j < 4; ++j)
      acc[i][j] = (floatx4)(0.f);

  for (int kk = 0; kk < K; kk += 32) {
    __syncthreads();
#pragma unroll
    for (int t = 0; t < 2; ++t) {
      const int r = wave * 32 + t * 16 + srow;
      gl2lds16(A  + (long)(m0 + r) * K + kk + schunk, &As[r * 32 + schunk]);
      gl2lds16(Bt + (long)(n0 + r) * K + kk + schunk, &Bs[r * 32 + schunk]);
    }
    __syncthreads();

    bf16x8 af[4], bfr[4];
#pragma unroll
    for (int i = 0; i < 4; ++i)
      af[i] = *(const bf16x8*)&As[(wm + i * 16 + lm) * 32 + quad * 8];
#pragma unroll
    for (int j = 0; j < 4; ++j)
      bfr[j] = *(const bf16x8*)&Bs[(wn + j * 16 + lm) * 32 + quad * 8];
#pragma unroll
    for (int i = 0; i < 4; ++i)
#pragma unroll
      for (int j = 0; j < 4; ++j)
        acc[i][j] = __builtin_amdgcn_mfma_f32_16x16x32_bf16(af[i], bfr[j],
                                                            acc[i][j], 0, 0, 0);
  }

  // epilogue: C/D layout col = lane&15, row = quad*4 + r
#pragma unroll
  for (int j = 0; j < 4; ++j) {
    const int cn = n0 + wn + j * 16 + lm;
    const float bv = HAS_BIAS ? bias[cn] : 0.f;
#pragma unroll
    for (int i = 0; i < 4; ++i) {
      const int rbase = m0 + wm + i * 16 + quad * 4;
#pragma unroll
      for (int r = 0; r < 4; ++r) {
        float v = alpha * acc[i][j][r];
        if (APPLY_EXP) v = __expf(v);
        v += bv;
        const long idx = bz * sC + (long)(rbase + r) * N + cn;
        if (OUT_BF16) ((bf16_t*)Cv)[idx] = (bf16_t)v;
        else          ((float*)Cv)[idx]  = v;
      }
    }
  }
}

// ---------------------------------------------------------------------------
// Tiled transpose -> bf16 (in: rows x cols row-major; out: cols x rows)
// ---------------------------------------------------------------------------
template<typename TIN>
__global__ void transpose_to_bf16(const TIN* __restrict__ in, bf16_t* __restrict__ out,
                                  int rows, int cols, long sIn, long sOut)
{
  __shared__ float tile[32][33];
  const int bz = blockIdx.z;
  in  += bz * sIn;
  out += bz * sOut;
  const int c0 = blockIdx.x * 32;
  const int r0 = blockIdx.y * 32;
  const int tx = threadIdx.x;   // 0..31
  const int ty = threadIdx.y;   // 0..7
#pragma unroll
  for (int i = 0; i < 32; i += 8)
    tile[ty + i][tx] = (float)in[(long)(r0 + ty + i) * cols + (c0 + tx)];
  __syncthreads();
#pragma unroll
  for (int i = 0; i < 32; i += 8)
    out[(long)(c0 + ty + i) * rows + (r0 + tx)] = (bf16_t)tile[tx][ty + i];
}

__global__ void cvt_f32_to_bf16(const float* __restrict__ in, bf16_t* __restrict__ out,
                                long n)
{
  const long i = ((long)blockIdx.x * blockDim.x + threadIdx.x) * 4;
  if (i >= n) return;
  const float4 v = *(const float4*)(in + i);
  struct alignas(8) B4 { bf16_t a, b, c, d; };
  B4 o; o.a = (bf16_t)v.x; o.b = (bf16_t)v.y; o.c = (bf16_t)v.z; o.d = (bf16_t)v.w;
  *(B4*)(out + i) = o;
}

// ---------------------------------------------------------------------------
// Column-sum of P over q: L[b][k] += sum_q P[b][q][k]. Coalesced bf16x8
// reads (thread t covers cols [8t,8t+8)), fp32 partials over 32 rows, then
// one atomicAdd per column. Grid: (S/32, 1, B), block 256.
// ---------------------------------------------------------------------------
__global__ __launch_bounds__(256)
void colsum_q(const bf16_t* __restrict__ Sc, float* __restrict__ L, int S)
{
  const bf16_t* p = Sc + (long)blockIdx.z * S * S + (long)blockIdx.x * 32 * S
                       + threadIdx.x * 8;
  float acc[8];
#pragma unroll
  for (int j = 0; j < 8; ++j) acc[j] = 0.f;
  for (int q = 0; q < 32; ++q) {
    const bf16x8 v = *(const bf16x8*)(p + (long)q * S);
#pragma unroll
    for (int j = 0; j < 8; ++j) acc[j] += (float)v[j];
  }
  float* Lb = L + blockIdx.z * S + threadIdx.x * 8;
#pragma unroll
  for (int j = 0; j < 8; ++j) atomicAdd(Lb + j, acc[j]);
}

__global__ void invert_vec(float* __restrict__ L, int n)
{
  const int i = blockIdx.x * blockDim.x + threadIdx.x;
  if (i < n) L[i] = 1.0f / L[i];
}

// In-place scale of P[b][q][k] by Linv[b][k]; bf16x8 per thread, coalesced.
__global__ __launch_bounds__(256)
void scale_cols(bf16_t* __restrict__ Sc, const float* __restrict__ Linv, int S)
{
  const long base = ((long)blockIdx.x * blockDim.x + threadIdx.x) * 8;
  const int  b  = (int)(base >> 22);            // S*S = 2^22
  const int  k0 = (int)(base & (long)(S - 1));  // S = 2^11
  const float* Lb = Linv + b * S + k0;
  bf16x8 v = *(const bf16x8*)(Sc + base);
#pragma unroll
  for (int j = 0; j < 8; ++j)
    v[j] = (bf16_t)((float)v[j] * Lb[j]);
  *(bf16x8*)(Sc + base) = v;
}

// ---------------------------------------------------------------------------
extern "C" void kernel_launch(void* const* d_in, const int* in_sizes, int n_in,
                              void* d_out, int out_size, void* d_ws, size_t ws_size,
                              hipStream_t stream)
{
  const int Bz = 4, S = 2048, F = 1024, DK = 1024;
  const int M = Bz * S;

  const float* x  = (const float*)d_in[0];
  const float* Wq = (const float*)d_in[1];
  const float* bq = (const float*)d_in[2];
  const float* Wk = (const float*)d_in[3];
  const float* bk = (const float*)d_in[4];
  const float* Wv = (const float*)d_in[5];
  const float* bv = (const float*)d_in[6];
  const float* Wo = (const float*)d_in[7];
  const float* bo = (const float*)d_in[8];

  char* ws = (char*)d_ws;
  const size_t MB = 1ull << 20;
  bf16_t* Xb  = (bf16_t*)(ws + 0);        // dead after QKV gemms
  bf16_t* V   = (bf16_t*)(ws + 16 * MB);  // dead after V-transpose
  bf16_t* Sc  = (bf16_t*)(ws + 0);        // 32MB scores/attn (over Xb+V)
  bf16_t* Q   = (bf16_t*)(ws + 32 * MB);  // dead after scores gemm
  bf16_t* Ctx = (bf16_t*)(ws + 32 * MB);
  bf16_t* Kb  = (bf16_t*)(ws + 48 * MB);
  bf16_t* Vt  = (bf16_t*)(ws + 64 * MB);
  bf16_t* WqT = (bf16_t*)(ws + 80 * MB);  // dead after Q projection
  bf16_t* WkT = (bf16_t*)(ws + 82 * MB);
  bf16_t* WvT = (bf16_t*)(ws + 84 * MB);
  bf16_t* WoT = (bf16_t*)(ws + 86 * MB);
  float*  L   = (float*)(ws + 80 * MB);   // 32KB, over dead WqT

  cvt_f32_to_bf16<<<(M * F) / 1024, 256, 0, stream>>>(x, Xb, (long)M * F);

  dim3 tb(32, 8);
  transpose_to_bf16<float><<<dim3(DK / 32, F / 32, 1), tb, 0, stream>>>(Wq, WqT, F, DK, 0, 0);
  transpose_to_bf16<float><<<dim3(DK / 32, F / 32, 1), tb, 0, stream>>>(Wk, WkT, F, DK, 0, 0);
  transpose_to_bf16<float><<<dim3(DK / 32, F / 32, 1), tb, 0, stream>>>(Wv, WvT, F, DK, 0, 0);
  transpose_to_bf16<float><<<dim3(F / 32, DK / 32, 1), tb, 0, stream>>>(Wo, WoT, DK, F, 0, 0);

  dim3 gp(DK / 128, M / 128, 1);
  gemm_nt<1, 1, 0><<<gp, 256, 0, stream>>>(Xb, WqT, Q,  bq, M, DK, F, 1.f, 0, 0, 0);
  gemm_nt<1, 1, 0><<<gp, 256, 0, stream>>>(Xb, WkT, Kb, bk, M, DK, F, 1.f, 0, 0, 0);
  gemm_nt<1, 1, 0><<<gp, 256, 0, stream>>>(Xb, WvT, V,  bv, M, DK, F, 1.f, 0, 0, 0);

  // V[b][s][d] -> Vt[b][d][s] (before Sc overwrites the V region)
  transpose_to_bf16<bf16_t><<<dim3(DK / 32, S / 32, Bz), tb, 0, stream>>>(
      V, Vt, S, DK, (long)S * DK, (long)S * DK);

  // P[b][q][k] = exp(Q.K / sqrt(dk))  -- no max-subtraction (scores ~N(0,1))
  gemm_nt<1, 0, 1><<<dim3(S / 128, S / 128, Bz), 256, 0, stream>>>(
      Q, Kb, Sc, nullptr, S, S, DK, 0.03125f,
      (long)S * DK, (long)S * DK, (long)S * S);

  // softmax over q == column-normalize P
  hipMemsetAsync(L, 0, (size_t)Bz * S * sizeof(float), stream);
  colsum_q<<<dim3(S / 32, 1, Bz), 256, 0, stream>>>(Sc, L, S);
  invert_vec<<<(Bz * S) / 256, 256, 0, stream>>>(L, Bz * S);
  scale_cols<<<((long)Bz * S * S / 8) / 256, 256, 0, stream>>>(Sc, L, S);

  // ctx[b][q][d] = attn[b] @ V[b]
  gemm_nt<1, 0, 0><<<dim3(DK / 128, S / 128, Bz), 256, 0, stream>>>(
      Sc, Vt, Ctx, nullptr, S, DK, S, 1.f,
      (long)S * S, (long)S * DK, (long)S * DK);

  gemm_nt<0, 1, 0><<<dim3(F / 128, M / 128, 1), 256, 0, stream>>>(
      Ctx, WoT, d_out, bo, M, F, DK, 1.f, 0, 0, 0);
}

// Round 3
// 338.274 us; speedup vs baseline: 1.4669x; 1.0834x over previous
//
#include <hip/hip_runtime.h>
#include <hip/hip_bf16.h>
#include <cstdint>

typedef __bf16 bf16_t;
typedef __bf16 bf16x8 __attribute__((ext_vector_type(8)));
typedef float  floatx4 __attribute__((ext_vector_type(4)));

typedef const __attribute__((address_space(1))) unsigned int* gptr_t;
typedef __attribute__((address_space(3))) unsigned int* lptr_t;

static __device__ __forceinline__ void gl2lds16(const bf16_t* g, bf16_t* l) {
  __builtin_amdgcn_global_load_lds((gptr_t)g, (lptr_t)l, 16, 0, 0);
}

// ---------------------------------------------------------------------------
// NT GEMM: C[M,N] = f(alpha * A[M,K] * B^T) + bias[n].
// bf16 in, fp32 accumulate, 128x128 tile, BK=32, 4 waves x (4x4) 16x16x32
// MFMAs (m97 structure). bf16 output goes through a per-wave padded LDS
// repack so global stores are bf16x8 (full 64B lines — fixes the 2x HBM
// write inflation rocprof showed with scalar bf16 stores).
// EXP_COLSUM: C=exp(alpha*acc), and column sums are atomicAdd'ed into L.
// SPLIT3: n in [0,3072) routed to 3 separate [M,1024] buffers (merged QKV).
// ---------------------------------------------------------------------------
template<int OUT_BF16, int HAS_BIAS, int EXP_COLSUM, int SPLIT3>
__global__ __launch_bounds__(256, 2)
void gemm_nt(const bf16_t* __restrict__ A, const bf16_t* __restrict__ Bt,
             void* __restrict__ Cv, const float* __restrict__ bias,
             float* __restrict__ L,
             int M, int N, int K, int ldC, float alpha,
             long sA, long sB, long sC,
             long co0, long co1, long co2)
{
  __shared__ __align__(16) bf16_t As[128 * 32];
  __shared__ __align__(16) bf16_t Bs[128 * 32];
  __shared__ __align__(16) bf16_t Ep[4 * 64 * 68];  // per-wave repack, pad 68

  const int bz = blockIdx.z;
  A  += bz * sA;
  Bt += bz * sB;

  const int gn0 = blockIdx.x * 128;   // global n (indexes Bt rows, bias, L)
  const int m0  = blockIdx.y * 128;
  const int tid  = threadIdx.x;
  const int lane = tid & 63;
  const int wave = tid >> 6;
  const int wm   = (wave >> 1) * 64;
  const int wn   = (wave & 1) * 64;
  const int lm   = lane & 15;
  const int quad = lane >> 4;

  // output chunk routing (uniform per block)
  int n0 = gn0;
  bf16_t* Cb = (bf16_t*)Cv;
  float*  Cf = (float*)Cv;
  if (SPLIT3) {
    const int which = gn0 >> 10;
    n0 = gn0 & 1023;
    Cb += (which == 0) ? co0 : (which == 1) ? co1 : co2;
  }

  const int srow   = lane >> 2;        // 0..15
  const int schunk = (lane & 3) * 8;   // 8 bf16 = 16B

  floatx4 acc[4][4];
#pragma unroll
  for (int i = 0; i < 4; ++i)
#pragma unroll
    for (int j = 0; j < 4; ++j)
      acc[i][j] = (floatx4)(0.f);

  for (int kk = 0; kk < K; kk += 32) {
    __syncthreads();
#pragma unroll
    for (int t = 0; t < 2; ++t) {
      const int r = wave * 32 + t * 16 + srow;
      gl2lds16(A  + (long)(m0  + r) * K + kk + schunk, &As[r * 32 + schunk]);
      gl2lds16(Bt + (long)(gn0 + r) * K + kk + schunk, &Bs[r * 32 + schunk]);
    }
    __syncthreads();

    bf16x8 af[4], bfr[4];
#pragma unroll
    for (int i = 0; i < 4; ++i)
      af[i] = *(const bf16x8*)&As[(wm + i * 16 + lm) * 32 + quad * 8];
#pragma unroll
    for (int j = 0; j < 4; ++j)
      bfr[j] = *(const bf16x8*)&Bs[(wn + j * 16 + lm) * 32 + quad * 8];
#pragma unroll
    for (int i = 0; i < 4; ++i)
#pragma unroll
      for (int j = 0; j < 4; ++j)
        acc[i][j] = __builtin_amdgcn_mfma_f32_16x16x32_bf16(af[i], bfr[j],
                                                            acc[i][j], 0, 0, 0);
  }

  // C/D layout: col = lane&15, row = quad*4 + r (measured m89/m91)
  if (OUT_BF16) {
    bf16_t* myEp = &Ep[wave * (64 * 68)];
    float cs[4] = {0.f, 0.f, 0.f, 0.f};
#pragma unroll
    for (int j = 0; j < 4; ++j) {
      const int cng = gn0 + wn + j * 16 + lm;
      const float bv = HAS_BIAS ? bias[cng] : 0.f;
#pragma unroll
      for (int i = 0; i < 4; ++i) {
#pragma unroll
        for (int r = 0; r < 4; ++r) {
          float v = alpha * acc[i][j][r];
          if (EXP_COLSUM) { v = __expf(v); cs[j] += v; }
          v += bv;
          myEp[(i * 16 + quad * 4 + r) * 68 + j * 16 + lm] = (bf16_t)v;
        }
      }
    }
    if (EXP_COLSUM) {
#pragma unroll
      for (int j = 0; j < 4; ++j) {
        float v = cs[j];
        v += __shfl_xor(v, 16);
        v += __shfl_xor(v, 32);
        if (quad == 0)
          atomicAdd(&L[bz * N + gn0 + wn + j * 16 + lm], v);
      }
    }
    // per-wave LDS region, DS pipe is in-order per wave: no barrier needed
    const int r8 = lane >> 3;
    const int c8 = lane & 7;
#pragma unroll
    for (int t = 0; t < 8; ++t) {
      const int row = t * 8 + r8;
      const bf16x8 vv = *(const bf16x8*)&myEp[row * 68 + c8 * 8];
      *(bf16x8*)&Cb[bz * sC + (long)(m0 + wm + row) * ldC + n0 + wn + c8 * 8] = vv;
    }
  } else {
    // fp32 out: 16 lanes x 4B = full 64B lines already
#pragma unroll
    for (int j = 0; j < 4; ++j) {
      const int cn = n0 + wn + j * 16 + lm;
      const float bv = HAS_BIAS ? bias[gn0 + wn + j * 16 + lm] : 0.f;
#pragma unroll
      for (int i = 0; i < 4; ++i) {
        const int rbase = m0 + wm + i * 16 + quad * 4;
#pragma unroll
        for (int r = 0; r < 4; ++r)
          Cf[bz * sC + (long)(rbase + r) * ldC + cn] = alpha * acc[i][j][r] + bv;
      }
    }
  }
}

// ---------------------------------------------------------------------------
// Tiled transpose -> bf16 (in: rows x cols row-major; out: cols x rows)
// ---------------------------------------------------------------------------
template<typename TIN>
__global__ void transpose_to_bf16(const TIN* __restrict__ in, bf16_t* __restrict__ out,
                                  int rows, int cols, long sIn, long sOut)
{
  __shared__ float tile[32][33];
  const int bz = blockIdx.z;
  in  += bz * sIn;
  out += bz * sOut;
  const int c0 = blockIdx.x * 32;
  const int r0 = blockIdx.y * 32;
  const int tx = threadIdx.x;
  const int ty = threadIdx.y;
#pragma unroll
  for (int i = 0; i < 32; i += 8)
    tile[ty + i][tx] = (float)in[(long)(r0 + ty + i) * cols + (c0 + tx)];
  __syncthreads();
#pragma unroll
  for (int i = 0; i < 32; i += 8)
    out[(long)(c0 + ty + i) * rows + (r0 + tx)] = (bf16_t)tile[tx][ty + i];
}

// three fp32 weights [F,DK] -> one bf16 [3*DK, F] (stacked transposes)
__global__ void transpose3_to_bf16(const float* __restrict__ w0,
                                   const float* __restrict__ w1,
                                   const float* __restrict__ w2,
                                   bf16_t* __restrict__ out, int rows, int cols)
{
  __shared__ float tile[32][33];
  const int z = blockIdx.z;
  const float* in = (z == 0) ? w0 : (z == 1) ? w1 : w2;
  out += (long)z * rows * cols;
  const int c0 = blockIdx.x * 32;
  const int r0 = blockIdx.y * 32;
  const int tx = threadIdx.x;
  const int ty = threadIdx.y;
#pragma unroll
  for (int i = 0; i < 32; i += 8)
    tile[ty + i][tx] = in[(long)(r0 + ty + i) * cols + (c0 + tx)];
  __syncthreads();
#pragma unroll
  for (int i = 0; i < 32; i += 8)
    out[(long)(c0 + ty + i) * rows + (r0 + tx)] = (bf16_t)tile[tx][ty + i];
}

__global__ void cvt_f32_to_bf16(const float* __restrict__ in, bf16_t* __restrict__ out,
                                long n)
{
  const long i = ((long)blockIdx.x * blockDim.x + threadIdx.x) * 4;
  if (i >= n) return;
  const float4 v = *(const float4*)(in + i);
  struct alignas(8) B4 { bf16_t a, b, c, d; };
  B4 o; o.a = (bf16_t)v.x; o.b = (bf16_t)v.y; o.c = (bf16_t)v.z; o.d = (bf16_t)v.w;
  *(B4*)(out + i) = o;
}

__global__ void concat3(const float* __restrict__ a, const float* __restrict__ b,
                        const float* __restrict__ c, float* __restrict__ o)
{
  const int i = blockIdx.x * blockDim.x + threadIdx.x;  // 0..3071
  const float* s = (i < 1024) ? a : (i < 2048) ? b : c;
  o[i] = s[i & 1023];
}

__global__ void invert_vec(float* __restrict__ L, int n)
{
  const int i = blockIdx.x * blockDim.x + threadIdx.x;
  if (i < n) L[i] = 1.0f / L[i];
}

// Vt[b][d][s] *= Linv[b][s]  (folds softmax denominator into V: the ctx GEMM
// then consumes raw P — replaces the 64MB scale_cols pass with 32MB here)
__global__ __launch_bounds__(256)
void scale_vt(bf16_t* __restrict__ Vt, const float* __restrict__ Linv, int S)
{
  const long base = ((long)blockIdx.x * blockDim.x + threadIdx.x) * 8;
  const int b  = (int)(base >> 21);           // DK*S = 2^21 elems per batch
  const int s0 = (int)(base & (long)(S - 1)); // S = 2^11
  const float* Lb = Linv + b * S + s0;
  bf16x8 v = *(const bf16x8*)(Vt + base);
#pragma unroll
  for (int j = 0; j < 8; ++j)
    v[j] = (bf16_t)((float)v[j] * Lb[j]);
  *(bf16x8*)(Vt + base) = v;
}

// ---------------------------------------------------------------------------
extern "C" void kernel_launch(void* const* d_in, const int* in_sizes, int n_in,
                              void* d_out, int out_size, void* d_ws, size_t ws_size,
                              hipStream_t stream)
{
  const int Bz = 4, S = 2048, F = 1024, DK = 1024;
  const int M = Bz * S;

  const float* x  = (const float*)d_in[0];
  const float* Wq = (const float*)d_in[1];
  const float* bq = (const float*)d_in[2];
  const float* Wk = (const float*)d_in[3];
  const float* bk = (const float*)d_in[4];
  const float* Wv = (const float*)d_in[5];
  const float* bv = (const float*)d_in[6];
  const float* Wo = (const float*)d_in[7];
  const float* bo = (const float*)d_in[8];

  char* ws = (char*)d_ws;
  const size_t MB = 1ull << 20;
  bf16_t* Xb   = (bf16_t*)(ws + 0);        // dead after QKV gemm
  bf16_t* V    = (bf16_t*)(ws + 16 * MB);  // dead after Vt transpose
  bf16_t* Sc   = (bf16_t*)(ws + 0);        // 32MB P (over Xb+V)
  bf16_t* Q    = (bf16_t*)(ws + 32 * MB);  // dead after scores gemm
  bf16_t* Ctx  = (bf16_t*)(ws + 32 * MB);
  bf16_t* Kb   = (bf16_t*)(ws + 48 * MB);
  bf16_t* Vt   = (bf16_t*)(ws + 64 * MB);
  float*  bcat = (float*)(ws + 64 * MB);   // 12KB over Vt (dead before Vt built)
  bf16_t* WcatT= (bf16_t*)(ws + 80 * MB);  // 6MB [3072][1024], dead after QKV
  float*  L    = (float*)(ws + 80 * MB);   // 32KB over dead WcatT
  bf16_t* WoT  = (bf16_t*)(ws + 86 * MB);  // 2MB

  // element offsets (from ws base as bf16*) for merged-QKV output routing
  const long coQ = 16 * MB;  // Q  at byte 32MB
  const long coK = 24 * MB;  // Kb at byte 48MB
  const long coV =  8 * MB;  // V  at byte 16MB

  cvt_f32_to_bf16<<<(M * F) / 1024, 256, 0, stream>>>(x, Xb, (long)M * F);

  dim3 tb(32, 8);
  transpose3_to_bf16<<<dim3(DK / 32, F / 32, 3), tb, 0, stream>>>(Wq, Wk, Wv, WcatT, F, DK);
  transpose_to_bf16<float><<<dim3(F / 32, DK / 32, 1), tb, 0, stream>>>(Wo, WoT, DK, F, 0, 0);
  concat3<<<12, 256, 0, stream>>>(bq, bk, bv, bcat);

  // merged Q/K/V projection: one GEMM, N=3072, outputs routed per n-block
  gemm_nt<1, 1, 0, 1><<<dim3(3 * DK / 128, M / 128, 1), 256, 0, stream>>>(
      Xb, WcatT, (void*)ws, bcat, nullptr, M, 3 * DK, F, DK, 1.f,
      0, 0, 0, coQ, coK, coV);

  // V[b][s][d] -> Vt[b][d][s]
  transpose_to_bf16<bf16_t><<<dim3(DK / 32, S / 32, Bz), tb, 0, stream>>>(
      V, Vt, S, DK, (long)S * DK, (long)S * DK);

  // P[b][q][k] = exp(Q.K/sqrt(dk)); column sums -> L (fused, atomics)
  hipMemsetAsync(L, 0, (size_t)Bz * S * sizeof(float), stream);
  gemm_nt<1, 0, 1, 0><<<dim3(S / 128, S / 128, Bz), 256, 0, stream>>>(
      Q, Kb, Sc, nullptr, L, S, S, DK, S, 0.03125f,
      (long)S * DK, (long)S * DK, (long)S * S, 0, 0, 0);

  invert_vec<<<(Bz * S) / 256, 256, 0, stream>>>(L, Bz * S);
  scale_vt<<<((long)Bz * DK * S / 8) / 256, 256, 0, stream>>>(Vt, L, S);

  // ctx[b][q][d] = P[b] @ (V/L)[b]
  gemm_nt<1, 0, 0, 0><<<dim3(DK / 128, S / 128, Bz), 256, 0, stream>>>(
      Sc, Vt, Ctx, nullptr, nullptr, S, DK, S, DK, 1.f,
      (long)S * S, (long)S * DK, (long)S * DK, 0, 0, 0);

  // out = ctx @ Wo + bo (fp32)
  gemm_nt<0, 1, 0, 0><<<dim3(F / 128, M / 128, 1), 256, 0, stream>>>(
      Ctx, WoT, d_out, bo, nullptr, M, F, DK, F, 1.f,
      0, 0, 0, 0, 0, 0);
}

// Round 4
// 318.958 us; speedup vs baseline: 1.5557x; 1.0606x over previous
//
#include <hip/hip_runtime.h>
#include <hip/hip_bf16.h>
#include <cstdint>

typedef __bf16 bf16_t;
typedef __bf16 bf16x8 __attribute__((ext_vector_type(8)));
typedef float  floatx4 __attribute__((ext_vector_type(4)));

typedef const __attribute__((address_space(1))) unsigned int* gptr_t;
typedef __attribute__((address_space(3))) unsigned int* lptr_t;

static __device__ __forceinline__ void gl2lds16(const bf16_t* g, bf16_t* l) {
  __builtin_amdgcn_global_load_lds((gptr_t)g, (lptr_t)l, 16, 0, 0);
}

// ---------------------------------------------------------------------------
// NT GEMM: C[M,N] = f(alpha * A[M,K] * B^T) + bias[n].
// bf16 in, fp32 accumulate, 128x128 tile, BK=32, 4 waves x (4x4) 16x16x32
// MFMAs (m97 structure). bf16 output: per-wave padded LDS repack -> bf16x8
// full-line stores. The repack buffer is UNIONED over As/Bs (dead after the
// K-loop; one barrier) and processed in 4 passes of 16 rows, so total LDS
// stays 16 KB -> occupancy is no longer LDS-limited (round-3 fix: 51 KB had
// dropped occupancy to 29%).
// EXP_COLSUM: C=exp(alpha*acc), column sums atomicAdd'ed into L.
// SPLIT3: n in [0,3072) routed to 3 separate [M,1024] buffers (merged QKV).
// ---------------------------------------------------------------------------
template<int OUT_BF16, int HAS_BIAS, int EXP_COLSUM, int SPLIT3>
__global__ __launch_bounds__(256, 4)
void gemm_nt(const bf16_t* __restrict__ A, const bf16_t* __restrict__ Bt,
             void* __restrict__ Cv, const float* __restrict__ bias,
             float* __restrict__ L,
             int M, int N, int K, int ldC, float alpha,
             long sA, long sB, long sC,
             long co0, long co1, long co2)
{
  __shared__ __align__(16) bf16_t smem[2 * 128 * 32];  // 16 KB total
  bf16_t* As = smem;
  bf16_t* Bs = smem + 128 * 32;

  const int bz = blockIdx.z;
  A  += bz * sA;
  Bt += bz * sB;

  const int gn0 = blockIdx.x * 128;   // global n (indexes Bt rows, bias, L)
  const int m0  = blockIdx.y * 128;
  const int tid  = threadIdx.x;
  const int lane = tid & 63;
  const int wave = tid >> 6;
  const int wm   = (wave >> 1) * 64;
  const int wn   = (wave & 1) * 64;
  const int lm   = lane & 15;
  const int quad = lane >> 4;

  // output chunk routing (uniform per block)
  int n0 = gn0;
  bf16_t* Cb = (bf16_t*)Cv;
  float*  Cf = (float*)Cv;
  if (SPLIT3) {
    const int which = gn0 >> 10;
    n0 = gn0 & 1023;
    Cb += (which == 0) ? co0 : (which == 1) ? co1 : co2;
  }

  const int srow   = lane >> 2;        // 0..15
  const int schunk = (lane & 3) * 8;   // 8 bf16 = 16B

  floatx4 acc[4][4];
#pragma unroll
  for (int i = 0; i < 4; ++i)
#pragma unroll
    for (int j = 0; j < 4; ++j)
      acc[i][j] = (floatx4)(0.f);

  for (int kk = 0; kk < K; kk += 32) {
    __syncthreads();
#pragma unroll
    for (int t = 0; t < 2; ++t) {
      const int r = wave * 32 + t * 16 + srow;
      gl2lds16(A  + (long)(m0  + r) * K + kk + schunk, &As[r * 32 + schunk]);
      gl2lds16(Bt + (long)(gn0 + r) * K + kk + schunk, &Bs[r * 32 + schunk]);
    }
    __syncthreads();

    bf16x8 af[4], bfr[4];
#pragma unroll
    for (int i = 0; i < 4; ++i)
      af[i] = *(const bf16x8*)&As[(wm + i * 16 + lm) * 32 + quad * 8];
#pragma unroll
    for (int j = 0; j < 4; ++j)
      bfr[j] = *(const bf16x8*)&Bs[(wn + j * 16 + lm) * 32 + quad * 8];
#pragma unroll
    for (int i = 0; i < 4; ++i)
#pragma unroll
      for (int j = 0; j < 4; ++j)
        acc[i][j] = __builtin_amdgcn_mfma_f32_16x16x32_bf16(af[i], bfr[j],
                                                            acc[i][j], 0, 0, 0);
  }

  // C/D layout: col = lane&15, row = quad*4 + r (measured m89/m91)
  if (OUT_BF16) {
    __syncthreads();                    // As/Bs dead for ALL waves -> reuse as Ep
    bf16_t* myEp = smem + wave * (16 * 68);  // 16 rows x 68 (padded), per wave
    const int r8 = lane >> 3;
    const int c8 = lane & 7;
    float cs[4] = {0.f, 0.f, 0.f, 0.f};
#pragma unroll
    for (int i = 0; i < 4; ++i) {       // 4 passes of 16 rows
#pragma unroll
      for (int j = 0; j < 4; ++j) {
        const float bv = HAS_BIAS ? bias[gn0 + wn + j * 16 + lm] : 0.f;
#pragma unroll
        for (int r = 0; r < 4; ++r) {
          float v = alpha * acc[i][j][r];
          if (EXP_COLSUM) { v = __expf(v); cs[j] += v; }
          v += bv;
          myEp[(quad * 4 + r) * 68 + j * 16 + lm] = (bf16_t)v;
        }
      }
      // per-wave region + in-order DS pipe: write->read needs no barrier
#pragma unroll
      for (int t = 0; t < 2; ++t) {
        const int row = t * 8 + r8;
        const bf16x8 vv = *(const bf16x8*)&myEp[row * 68 + c8 * 8];
        *(bf16x8*)&Cb[bz * sC + (long)(m0 + wm + i * 16 + row) * ldC
                      + n0 + wn + c8 * 8] = vv;
      }
    }
    if (EXP_COLSUM) {
#pragma unroll
      for (int j = 0; j < 4; ++j) {
        float v = cs[j];
        v += __shfl_xor(v, 16);
        v += __shfl_xor(v, 32);
        if (quad == 0)
          atomicAdd(&L[bz * N + gn0 + wn + j * 16 + lm], v);
      }
    }
  } else {
    // fp32 out: 16 lanes x 4B = full 64B lines already
#pragma unroll
    for (int j = 0; j < 4; ++j) {
      const int cn = n0 + wn + j * 16 + lm;
      const float bv = HAS_BIAS ? bias[gn0 + wn + j * 16 + lm] : 0.f;
#pragma unroll
      for (int i = 0; i < 4; ++i) {
        const int rbase = m0 + wm + i * 16 + quad * 4;
#pragma unroll
        for (int r = 0; r < 4; ++r)
          Cf[bz * sC + (long)(rbase + r) * ldC + cn] = alpha * acc[i][j][r] + bv;
      }
    }
  }
}

// ---------------------------------------------------------------------------
// Tiled transpose -> bf16 (in: rows x cols row-major; out: cols x rows)
// ---------------------------------------------------------------------------
template<typename TIN>
__global__ void transpose_to_bf16(const TIN* __restrict__ in, bf16_t* __restrict__ out,
                                  int rows, int cols, long sIn, long sOut)
{
  __shared__ float tile[32][33];
  const int bz = blockIdx.z;
  in  += bz * sIn;
  out += bz * sOut;
  const int c0 = blockIdx.x * 32;
  const int r0 = blockIdx.y * 32;
  const int tx = threadIdx.x;
  const int ty = threadIdx.y;
#pragma unroll
  for (int i = 0; i < 32; i += 8)
    tile[ty + i][tx] = (float)in[(long)(r0 + ty + i) * cols + (c0 + tx)];
  __syncthreads();
#pragma unroll
  for (int i = 0; i < 32; i += 8)
    out[(long)(c0 + ty + i) * rows + (r0 + tx)] = (bf16_t)tile[tx][ty + i];
}

// three fp32 weights [F,DK] -> one bf16 [3*DK, F] (stacked transposes)
__global__ void transpose3_to_bf16(const float* __restrict__ w0,
                                   const float* __restrict__ w1,
                                   const float* __restrict__ w2,
                                   bf16_t* __restrict__ out, int rows, int cols)
{
  __shared__ float tile[32][33];
  const int z = blockIdx.z;
  const float* in = (z == 0) ? w0 : (z == 1) ? w1 : w2;
  out += (long)z * rows * cols;
  const int c0 = blockIdx.x * 32;
  const int r0 = blockIdx.y * 32;
  const int tx = threadIdx.x;
  const int ty = threadIdx.y;
#pragma unroll
  for (int i = 0; i < 32; i += 8)
    tile[ty + i][tx] = in[(long)(r0 + ty + i) * cols + (c0 + tx)];
  __syncthreads();
#pragma unroll
  for (int i = 0; i < 32; i += 8)
    out[(long)(c0 + ty + i) * rows + (r0 + tx)] = (bf16_t)tile[tx][ty + i];
}

__global__ void cvt_f32_to_bf16(const float* __restrict__ in, bf16_t* __restrict__ out,
                                long n)
{
  const long i = ((long)blockIdx.x * blockDim.x + threadIdx.x) * 4;
  if (i >= n) return;
  const float4 v = *(const float4*)(in + i);
  struct alignas(8) B4 { bf16_t a, b, c, d; };
  B4 o; o.a = (bf16_t)v.x; o.b = (bf16_t)v.y; o.c = (bf16_t)v.z; o.d = (bf16_t)v.w;
  *(B4*)(out + i) = o;
}

__global__ void concat3(const float* __restrict__ a, const float* __restrict__ b,
                        const float* __restrict__ c, float* __restrict__ o)
{
  const int i = blockIdx.x * blockDim.x + threadIdx.x;  // 0..3071
  const float* s = (i < 1024) ? a : (i < 2048) ? b : c;
  o[i] = s[i & 1023];
}

// Vt[b][d][s] *= 1/L[b][s]  (folds softmax denominator into V; ctx GEMM then
// consumes raw P). Divide inline — kernel is memory-bound, saves a launch.
__global__ __launch_bounds__(256)
void scale_vt(bf16_t* __restrict__ Vt, const float* __restrict__ L, int S)
{
  const long base = ((long)blockIdx.x * blockDim.x + threadIdx.x) * 8;
  const int b  = (int)(base >> 21);           // DK*S = 2^21 elems per batch
  const int s0 = (int)(base & (long)(S - 1)); // S = 2^11
  const float* Lb = L + b * S + s0;
  bf16x8 v = *(const bf16x8*)(Vt + base);
#pragma unroll
  for (int j = 0; j < 8; ++j)
    v[j] = (bf16_t)((float)v[j] / Lb[j]);
  *(bf16x8*)(Vt + base) = v;
}

// ---------------------------------------------------------------------------
extern "C" void kernel_launch(void* const* d_in, const int* in_sizes, int n_in,
                              void* d_out, int out_size, void* d_ws, size_t ws_size,
                              hipStream_t stream)
{
  const int Bz = 4, S = 2048, F = 1024, DK = 1024;
  const int M = Bz * S;

  const float* x  = (const float*)d_in[0];
  const float* Wq = (const float*)d_in[1];
  const float* bq = (const float*)d_in[2];
  const float* Wk = (const float*)d_in[3];
  const float* bk = (const float*)d_in[4];
  const float* Wv = (const float*)d_in[5];
  const float* bv = (const float*)d_in[6];
  const float* Wo = (const float*)d_in[7];
  const float* bo = (const float*)d_in[8];

  char* ws = (char*)d_ws;
  const size_t MB = 1ull << 20;
  bf16_t* Xb   = (bf16_t*)(ws + 0);        // dead after QKV gemm
  bf16_t* V    = (bf16_t*)(ws + 16 * MB);  // dead after Vt transpose
  bf16_t* Sc   = (bf16_t*)(ws + 0);        // 32MB P (over Xb+V)
  bf16_t* Q    = (bf16_t*)(ws + 32 * MB);  // dead after scores gemm
  bf16_t* Ctx  = (bf16_t*)(ws + 32 * MB);
  bf16_t* Kb   = (bf16_t*)(ws + 48 * MB);
  bf16_t* Vt   = (bf16_t*)(ws + 64 * MB);
  float*  bcat = (float*)(ws + 64 * MB);   // 12KB over Vt (dead before Vt built)
  bf16_t* WcatT= (bf16_t*)(ws + 80 * MB);  // 6MB [3072][1024], dead after QKV
  float*  L    = (float*)(ws + 80 * MB);   // 32KB over dead WcatT
  bf16_t* WoT  = (bf16_t*)(ws + 86 * MB);  // 2MB

  // element offsets (from ws base as bf16*) for merged-QKV output routing
  const long coQ = 16 * MB;  // Q  at byte 32MB
  const long coK = 24 * MB;  // Kb at byte 48MB
  const long coV =  8 * MB;  // V  at byte 16MB

  cvt_f32_to_bf16<<<(M * F) / 1024, 256, 0, stream>>>(x, Xb, (long)M * F);

  dim3 tb(32, 8);
  transpose3_to_bf16<<<dim3(DK / 32, F / 32, 3), tb, 0, stream>>>(Wq, Wk, Wv, WcatT, F, DK);
  transpose_to_bf16<float><<<dim3(F / 32, DK / 32, 1), tb, 0, stream>>>(Wo, WoT, DK, F, 0, 0);
  concat3<<<12, 256, 0, stream>>>(bq, bk, bv, bcat);

  // merged Q/K/V projection: one GEMM, N=3072, outputs routed per n-block
  gemm_nt<1, 1, 0, 1><<<dim3(3 * DK / 128, M / 128, 1), 256, 0, stream>>>(
      Xb, WcatT, (void*)ws, bcat, nullptr, M, 3 * DK, F, DK, 1.f,
      0, 0, 0, coQ, coK, coV);

  // V[b][s][d] -> Vt[b][d][s]
  transpose_to_bf16<bf16_t><<<dim3(DK / 32, S / 32, Bz), tb, 0, stream>>>(
      V, Vt, S, DK, (long)S * DK, (long)S * DK);

  // P[b][q][k] = exp(Q.K/sqrt(dk)); column sums -> L (fused, atomics)
  hipMemsetAsync(L, 0, (size_t)Bz * S * sizeof(float), stream);
  gemm_nt<1, 0, 1, 0><<<dim3(S / 128, S / 128, Bz), 256, 0, stream>>>(
      Q, Kb, Sc, nullptr, L, S, S, DK, S, 0.03125f,
      (long)S * DK, (long)S * DK, (long)S * S, 0, 0, 0);

  scale_vt<<<((long)Bz * DK * S / 8) / 256, 256, 0, stream>>>(Vt, L, S);

  // ctx[b][q][d] = P[b] @ (V/L)[b]
  gemm_nt<1, 0, 0, 0><<<dim3(DK / 128, S / 128, Bz), 256, 0, stream>>>(
      Sc, Vt, Ctx, nullptr, nullptr, S, DK, S, DK, 1.f,
      (long)S * S, (long)S * DK, (long)S * DK, 0, 0, 0);

  // out = ctx @ Wo + bo (fp32)
  gemm_nt<0, 1, 0, 0><<<dim3(F / 128, M / 128, 1), 256, 0, stream>>>(
      Ctx, WoT, d_out, bo, nullptr, M, F, DK, F, 1.f,
      0, 0, 0, 0, 0, 0);
}

// Round 5
// 307.500 us; speedup vs baseline: 1.6137x; 1.0373x over previous
//
#include <hip/hip_runtime.h>
#include <hip/hip_bf16.h>
#include <cstdint>

typedef __bf16 bf16_t;
typedef __bf16 bf16x8 __attribute__((ext_vector_type(8)));
typedef float  floatx4 __attribute__((ext_vector_type(4)));

typedef const __attribute__((address_space(1))) unsigned int* gptr_t;
typedef __attribute__((address_space(3))) unsigned int* lptr_t;

static __device__ __forceinline__ void gl2lds16(const bf16_t* g, bf16_t* l) {
  __builtin_amdgcn_global_load_lds((gptr_t)g, (lptr_t)l, 16, 0, 0);
}

// ---------------------------------------------------------------------------
// NT GEMM: C[M,N] = f(alpha * A[M,K] * B^T) + bias[n].
// bf16 in, fp32 accumulate, 128x128 tile, BK=32, 4 waves x (4x4) 16x16x32
// MFMAs (m97 structure). bf16 out goes through a per-wave LDS repack unioned
// over As/Bs (16 KB total) -> full-line bf16x8 stores.
// XCD swizzle: block id & 7 selects XCD (round-robin dispatch heuristic);
// each XCD gets a contiguous row-major stripe of tiles so its A-rows stay
// L2-resident (round-4 counters: FETCH 72.7MB vs 22MB unique).
// EXP_COLSUM: C=exp(alpha*acc), column sums atomicAdd'ed into L.
// SPLIT3 (merged QKV): n in [0,3072) routed to 3 buffers with per-chunk bias
// pointers; the V chunk (which==2) is stored TRANSPOSED (Vt[b][d][s]) via a
// per-wave transposed LDS repack — the standalone V-transpose kernel is gone.
// ---------------------------------------------------------------------------
template<int OUT_BF16, int HAS_BIAS, int EXP_COLSUM, int SPLIT3>
__global__ __launch_bounds__(256, 4)
void gemm_nt(const bf16_t* __restrict__ A, const bf16_t* __restrict__ Bt,
             void* __restrict__ Cv,
             const float* __restrict__ b0, const float* __restrict__ b1,
             const float* __restrict__ b2,
             float* __restrict__ L,
             int M, int N, int K, int ldC, float alpha,
             long sA, long sB, long sC,
             long co0, long co1, long co2,
             int mbShift, int ldTv, long sTv)
{
  __shared__ __align__(16) bf16_t smem[2 * 128 * 32];  // 16 KB total
  bf16_t* As = smem;
  bf16_t* Bs = smem + 128 * 32;

  const int bz = blockIdx.z;
  A  += bz * sA;
  Bt += bz * sB;

  // ---- XCD-aware swizzle (heuristic: hw assigns id%8 -> XCD; grids here
  // have nb%8==0 so per-z slices keep the same mapping) ----
  int bx = blockIdx.x, by = blockIdx.y;
  {
    const int gx = gridDim.x;
    const int nb = gx * gridDim.y;
    if ((nb & 7) == 0) {
      const int id = bx + gx * by;
      const int T  = (id & 7) * (nb >> 3) + (id >> 3);
      bx = T % gx;
      by = T / gx;
    }
  }

  const int gn0 = bx * 128;   // global n (indexes Bt rows, L)
  const int m0  = by * 128;
  const int tid  = threadIdx.x;
  const int lane = tid & 63;
  const int wave = tid >> 6;
  const int wm   = (wave >> 1) * 64;
  const int wn   = (wave & 1) * 64;
  const int lm   = lane & 15;
  const int quad = lane >> 4;

  // output chunk routing (uniform per block)
  int n0 = gn0;
  int which = 0;
  bf16_t* Cb = (bf16_t*)Cv;
  float*  Cf = (float*)Cv;
  const float* bias = b0;
  if (SPLIT3) {
    which = gn0 >> 10;
    n0 = gn0 & 1023;
    Cb += (which == 0) ? co0 : (which == 1) ? co1 : co2;
    bias = (which == 0) ? b0 : (which == 1) ? b1 : b2;
  }

  const int srow   = lane >> 2;        // 0..15
  const int schunk = (lane & 3) * 8;   // 8 bf16 = 16B

  floatx4 acc[4][4];
#pragma unroll
  for (int i = 0; i < 4; ++i)
#pragma unroll
    for (int j = 0; j < 4; ++j)
      acc[i][j] = (floatx4)(0.f);

  for (int kk = 0; kk < K; kk += 32) {
    __syncthreads();
#pragma unroll
    for (int t = 0; t < 2; ++t) {
      const int r = wave * 32 + t * 16 + srow;
      gl2lds16(A  + (long)(m0  + r) * K + kk + schunk, &As[r * 32 + schunk]);
      gl2lds16(Bt + (long)(gn0 + r) * K + kk + schunk, &Bs[r * 32 + schunk]);
    }
    __syncthreads();

    bf16x8 af[4], bfr[4];
#pragma unroll
    for (int i = 0; i < 4; ++i)
      af[i] = *(const bf16x8*)&As[(wm + i * 16 + lm) * 32 + quad * 8];
#pragma unroll
    for (int j = 0; j < 4; ++j)
      bfr[j] = *(const bf16x8*)&Bs[(wn + j * 16 + lm) * 32 + quad * 8];
#pragma unroll
    for (int i = 0; i < 4; ++i)
#pragma unroll
      for (int j = 0; j < 4; ++j)
        acc[i][j] = __builtin_amdgcn_mfma_f32_16x16x32_bf16(af[i], bfr[j],
                                                            acc[i][j], 0, 0, 0);
  }

  // C/D layout: col = lane&15, row = quad*4 + r (measured m89/m91)
  if (SPLIT3 && which == 2) {
    // ---- transposed epilogue: store Vt[b][d][s] directly ----
    __syncthreads();                    // As/Bs dead -> reuse as per-wave EpT
    bf16_t* myT = smem + wave * (16 * 68);   // [16 n][64 m, pad 68]
    const int b  = m0 >> mbShift;
    const int s0 = m0 & ((1 << mbShift) - 1);
    const int r8 = lane >> 3;
    const int c8 = lane & 7;
#pragma unroll
    for (int j = 0; j < 4; ++j) {       // 16 d-values per pass
      const float bv = HAS_BIAS ? bias[n0 + wn + j * 16 + lm] : 0.f;
#pragma unroll
      for (int i = 0; i < 4; ++i)
#pragma unroll
        for (int r = 0; r < 4; ++r)
          myT[lm * 68 + i * 16 + quad * 4 + r] = (bf16_t)(acc[i][j][r] + bv);
      // per-wave region + in-order DS pipe: write->read needs no barrier
#pragma unroll
      for (int t = 0; t < 2; ++t) {
        const int nr = t * 8 + r8;      // d within pass
        const bf16x8 vv = *(const bf16x8*)&myT[nr * 68 + c8 * 8];
        *(bf16x8*)&Cb[(long)b * sTv + (long)(n0 + wn + j * 16 + nr) * ldTv
                      + s0 + wm + c8 * 8] = vv;
      }
    }
  } else if (OUT_BF16) {
    __syncthreads();                    // As/Bs dead -> reuse as per-wave Ep
    bf16_t* myEp = smem + wave * (16 * 68);  // 16 rows x 68 (padded)
    const int r8 = lane >> 3;
    const int c8 = lane & 7;
    float cs[4] = {0.f, 0.f, 0.f, 0.f};
#pragma unroll
    for (int i = 0; i < 4; ++i) {       // 4 passes of 16 rows
#pragma unroll
      for (int j = 0; j < 4; ++j) {
        const float bv = HAS_BIAS ? bias[n0 + wn + j * 16 + lm] : 0.f;
#pragma unroll
        for (int r = 0; r < 4; ++r) {
          float v = alpha * acc[i][j][r];
          if (EXP_COLSUM) { v = __expf(v); cs[j] += v; }
          v += bv;
          myEp[(quad * 4 + r) * 68 + j * 16 + lm] = (bf16_t)v;
        }
      }
#pragma unroll
      for (int t = 0; t < 2; ++t) {
        const int row = t * 8 + r8;
        const bf16x8 vv = *(const bf16x8*)&myEp[row * 68 + c8 * 8];
        *(bf16x8*)&Cb[bz * sC + (long)(m0 + wm + i * 16 + row) * ldC
                      + n0 + wn + c8 * 8] = vv;
      }
    }
    if (EXP_COLSUM) {
#pragma unroll
      for (int j = 0; j < 4; ++j) {
        float v = cs[j];
        v += __shfl_xor(v, 16);
        v += __shfl_xor(v, 32);
        if (quad == 0)
          atomicAdd(&L[bz * N + gn0 + wn + j * 16 + lm], v);
      }
    }
  } else {
    // fp32 out: 16 lanes x 4B = full 64B lines already
#pragma unroll
    for (int j = 0; j < 4; ++j) {
      const int cn = n0 + wn + j * 16 + lm;
      const float bv = HAS_BIAS ? bias[n0 + wn + j * 16 + lm] : 0.f;
#pragma unroll
      for (int i = 0; i < 4; ++i) {
        const int rbase = m0 + wm + i * 16 + quad * 4;
#pragma unroll
        for (int r = 0; r < 4; ++r)
          Cf[bz * sC + (long)(rbase + r) * ldC + cn] = alpha * acc[i][j][r] + bv;
      }
    }
  }
}

// ---------------------------------------------------------------------------
// Four 1024x1024 fp32 weights -> bf16 transposes in one dispatch:
// z<3 -> WcatT + z*1024*1024 (Wq,Wk,Wv), z==3 -> WoT.
// ---------------------------------------------------------------------------
__global__ void transpose4_to_bf16(const float* __restrict__ w0,
                                   const float* __restrict__ w1,
                                   const float* __restrict__ w2,
                                   const float* __restrict__ w3,
                                   bf16_t* __restrict__ outQKV,
                                   bf16_t* __restrict__ outO)
{
  __shared__ float tile[32][33];
  const int z = blockIdx.z;
  const float* in = (z == 0) ? w0 : (z == 1) ? w1 : (z == 2) ? w2 : w3;
  bf16_t* out = (z < 3) ? outQKV + (long)z * 1024 * 1024 : outO;
  const int c0 = blockIdx.x * 32;
  const int r0 = blockIdx.y * 32;
  const int tx = threadIdx.x;
  const int ty = threadIdx.y;
#pragma unroll
  for (int i = 0; i < 32; i += 8)
    tile[ty + i][tx] = in[(long)(r0 + ty + i) * 1024 + (c0 + tx)];
  __syncthreads();
#pragma unroll
  for (int i = 0; i < 32; i += 8)
    out[(long)(c0 + ty + i) * 1024 + (r0 + tx)] = (bf16_t)tile[tx][ty + i];
}

__global__ void cvt_f32_to_bf16(const float* __restrict__ in, bf16_t* __restrict__ out,
                                long n)
{
  const long i = ((long)blockIdx.x * blockDim.x + threadIdx.x) * 4;
  if (i >= n) return;
  const float4 v = *(const float4*)(in + i);
  struct alignas(8) B4 { bf16_t a, b, c, d; };
  B4 o; o.a = (bf16_t)v.x; o.b = (bf16_t)v.y; o.c = (bf16_t)v.z; o.d = (bf16_t)v.w;
  *(B4*)(out + i) = o;
}

// Vt[b][d][s] *= 1/L[b][s]  (folds softmax denominator into V; ctx GEMM then
// consumes raw P).
__global__ __launch_bounds__(256)
void scale_vt(bf16_t* __restrict__ Vt, const float* __restrict__ L, int S)
{
  const long base = ((long)blockIdx.x * blockDim.x + threadIdx.x) * 8;
  const int b  = (int)(base >> 21);           // DK*S = 2^21 elems per batch
  const int s0 = (int)(base & (long)(S - 1)); // S = 2^11
  const float* Lb = L + b * S + s0;
  bf16x8 v = *(const bf16x8*)(Vt + base);
#pragma unroll
  for (int j = 0; j < 8; ++j)
    v[j] = (bf16_t)((float)v[j] / Lb[j]);
  *(bf16x8*)(Vt + base) = v;
}

// ---------------------------------------------------------------------------
extern "C" void kernel_launch(void* const* d_in, const int* in_sizes, int n_in,
                              void* d_out, int out_size, void* d_ws, size_t ws_size,
                              hipStream_t stream)
{
  const int Bz = 4, S = 2048, F = 1024, DK = 1024;
  const int M = Bz * S;

  const float* x  = (const float*)d_in[0];
  const float* Wq = (const float*)d_in[1];
  const float* bq = (const float*)d_in[2];
  const float* Wk = (const float*)d_in[3];
  const float* bk = (const float*)d_in[4];
  const float* Wv = (const float*)d_in[5];
  const float* bv = (const float*)d_in[6];
  const float* Wo = (const float*)d_in[7];
  const float* bo = (const float*)d_in[8];

  char* ws = (char*)d_ws;
  const size_t MB = 1ull << 20;
  bf16_t* Xb   = (bf16_t*)(ws + 0);        // dead after QKV gemm
  bf16_t* Sc   = (bf16_t*)(ws + 0);        // 32MB P (over dead Xb)
  bf16_t* Q    = (bf16_t*)(ws + 32 * MB);  // dead after scores gemm
  bf16_t* Ctx  = (bf16_t*)(ws + 32 * MB);
  bf16_t* Kb   = (bf16_t*)(ws + 48 * MB);
  bf16_t* Vt   = (bf16_t*)(ws + 64 * MB);  // written DIRECTLY by QKV epilogue
  bf16_t* WcatT= (bf16_t*)(ws + 80 * MB);  // 6MB [3072][1024], dead after QKV
  float*  L    = (float*)(ws + 80 * MB);   // 32KB over dead WcatT
  bf16_t* WoT  = (bf16_t*)(ws + 86 * MB);  // 2MB

  // element offsets (from ws base as bf16*) for merged-QKV output routing
  const long coQ = 16 * MB;  // Q  at byte 32MB
  const long coK = 24 * MB;  // Kb at byte 48MB
  const long coV = 32 * MB;  // Vt at byte 64MB (transposed store)

  cvt_f32_to_bf16<<<(M * F) / 1024, 256, 0, stream>>>(x, Xb, (long)M * F);

  transpose4_to_bf16<<<dim3(32, 32, 4), dim3(32, 8), 0, stream>>>(
      Wq, Wk, Wv, Wo, WcatT, WoT);

  // merged Q/K/V projection; V chunk stored transposed as Vt[b][d][s]
  gemm_nt<1, 1, 0, 1><<<dim3(3 * DK / 128, M / 128, 1), 256, 0, stream>>>(
      Xb, WcatT, (void*)ws, bq, bk, bv, nullptr, M, 3 * DK, F, DK, 1.f,
      0, 0, 0, coQ, coK, coV, 11, S, (long)DK * S);

  // P[b][q][k] = exp(Q.K/sqrt(dk)); column sums -> L (fused, atomics)
  hipMemsetAsync(L, 0, (size_t)Bz * S * sizeof(float), stream);
  gemm_nt<1, 0, 1, 0><<<dim3(S / 128, S / 128, Bz), 256, 0, stream>>>(
      Q, Kb, Sc, nullptr, nullptr, nullptr, L, S, S, DK, S, 0.03125f,
      (long)S * DK, (long)S * DK, (long)S * S, 0, 0, 0, 0, 0, 0);

  scale_vt<<<((long)Bz * DK * S / 8) / 256, 256, 0, stream>>>(Vt, L, S);

  // ctx[b][q][d] = P[b] @ (V/L)[b]
  gemm_nt<1, 0, 0, 0><<<dim3(DK / 128, S / 128, Bz), 256, 0, stream>>>(
      Sc, Vt, Ctx, nullptr, nullptr, nullptr, nullptr, S, DK, S, DK, 1.f,
      (long)S * S, (long)S * DK, (long)S * DK, 0, 0, 0, 0, 0, 0);

  // out = ctx @ Wo + bo (fp32)
  gemm_nt<0, 1, 0, 0><<<dim3(F / 128, M / 128, 1), 256, 0, stream>>>(
      Ctx, WoT, d_out, bo, nullptr, nullptr, nullptr, M, F, DK, F, 1.f,
      0, 0, 0, 0, 0, 0, 0, 0, 0);
}

// Round 6
// 288.830 us; speedup vs baseline: 1.7180x; 1.0646x over previous
//
#include <hip/hip_runtime.h>
#include <hip/hip_bf16.h>
#include <cstdint>

typedef __bf16 bf16_t;
typedef __bf16 bf16x8 __attribute__((ext_vector_type(8)));
typedef float  floatx4 __attribute__((ext_vector_type(4)));

typedef const __attribute__((address_space(1))) unsigned int* gptr_t;
typedef __attribute__((address_space(3))) unsigned int* lptr_t;

static __device__ __forceinline__ void gl2lds16(const bf16_t* g, bf16_t* l) {
  __builtin_amdgcn_global_load_lds((gptr_t)g, (lptr_t)l, 16, 0, 0);
}

// ---------------------------------------------------------------------------
// NT GEMM: C[M,N] = f(alpha * A[M,K] * B^T) + bias[n].
// bf16 in, fp32 accumulate, 128x128 tile, 4 waves x (4x4) 16x16x32 MFMAs.
// K-loop: BK=64 as TWO BK=32 panels staged per barrier pair (32 KB LDS) —
// halves the vmcnt(0)+s_barrier drains vs the m97 2-barrier/BK=32 structure
// (m132's BK=128 regression was 64KB-LDS occupancy loss; 32KB keeps 4
// blocks/CU). Per-panel layout identical to BK=32 -> same bank profile.
// bf16 out: per-wave LDS repack unioned over panels -> full-line bf16x8.
// XCD swizzle: id&7 -> XCD stripe for A-row L2 residency.
// EXP_COLSUM: C=exp(alpha*acc), column sums atomicAdd'ed into L.
// SPLIT3 (merged QKV): V chunk stored transposed (Vt[b][d][s]) directly.
// ---------------------------------------------------------------------------
template<int OUT_BF16, int HAS_BIAS, int EXP_COLSUM, int SPLIT3>
__global__ __launch_bounds__(256, 4)
void gemm_nt(const bf16_t* __restrict__ A, const bf16_t* __restrict__ Bt,
             void* __restrict__ Cv,
             const float* __restrict__ b0, const float* __restrict__ b1,
             const float* __restrict__ b2,
             float* __restrict__ L,
             int M, int N, int K, int ldC, float alpha,
             long sA, long sB, long sC,
             long co0, long co1, long co2,
             int mbShift, int ldTv, long sTv)
{
  __shared__ __align__(16) bf16_t smem[4 * 128 * 32];  // 32 KB
  bf16_t* As0 = smem;
  bf16_t* Bs0 = smem + 4096;
  bf16_t* As1 = smem + 8192;
  bf16_t* Bs1 = smem + 12288;

  const int bz = blockIdx.z;
  A  += bz * sA;
  Bt += bz * sB;

  // XCD-aware swizzle (hw round-robins id%8 across XCDs; nb%8==0 here)
  int bx = blockIdx.x, by = blockIdx.y;
  {
    const int gx = gridDim.x;
    const int nb = gx * gridDim.y;
    if ((nb & 7) == 0) {
      const int id = bx + gx * by;
      const int T  = (id & 7) * (nb >> 3) + (id >> 3);
      bx = T % gx;
      by = T / gx;
    }
  }

  const int gn0 = bx * 128;
  const int m0  = by * 128;
  const int tid  = threadIdx.x;
  const int lane = tid & 63;
  const int wave = tid >> 6;
  const int wm   = (wave >> 1) * 64;
  const int wn   = (wave & 1) * 64;
  const int lm   = lane & 15;
  const int quad = lane >> 4;

  int n0 = gn0;
  int which = 0;
  bf16_t* Cb = (bf16_t*)Cv;
  float*  Cf = (float*)Cv;
  const float* bias = b0;
  if (SPLIT3) {
    which = gn0 >> 10;
    n0 = gn0 & 1023;
    Cb += (which == 0) ? co0 : (which == 1) ? co1 : co2;
    bias = (which == 0) ? b0 : (which == 1) ? b1 : b2;
  }

  const int srow   = lane >> 2;        // 0..15
  const int schunk = (lane & 3) * 8;   // 8 bf16 = 16B

  floatx4 acc[4][4];
#pragma unroll
  for (int i = 0; i < 4; ++i)
#pragma unroll
    for (int j = 0; j < 4; ++j)
      acc[i][j] = (floatx4)(0.f);

  for (int kk = 0; kk < K; kk += 64) {
    __syncthreads();
#pragma unroll
    for (int t = 0; t < 2; ++t) {
      const int r = wave * 32 + t * 16 + srow;
      const long ar = (long)(m0  + r) * K + kk + schunk;
      const long br = (long)(gn0 + r) * K + kk + schunk;
      gl2lds16(A  + ar,      &As0[r * 32 + schunk]);
      gl2lds16(A  + ar + 32, &As1[r * 32 + schunk]);
      gl2lds16(Bt + br,      &Bs0[r * 32 + schunk]);
      gl2lds16(Bt + br + 32, &Bs1[r * 32 + schunk]);
    }
    __syncthreads();

    {
      bf16x8 af[4], bfr[4];
#pragma unroll
      for (int i = 0; i < 4; ++i)
        af[i] = *(const bf16x8*)&As0[(wm + i * 16 + lm) * 32 + quad * 8];
#pragma unroll
      for (int j = 0; j < 4; ++j)
        bfr[j] = *(const bf16x8*)&Bs0[(wn + j * 16 + lm) * 32 + quad * 8];
#pragma unroll
      for (int i = 0; i < 4; ++i)
#pragma unroll
        for (int j = 0; j < 4; ++j)
          acc[i][j] = __builtin_amdgcn_mfma_f32_16x16x32_bf16(af[i], bfr[j],
                                                              acc[i][j], 0, 0, 0);
    }
    {
      bf16x8 af[4], bfr[4];
#pragma unroll
      for (int i = 0; i < 4; ++i)
        af[i] = *(const bf16x8*)&As1[(wm + i * 16 + lm) * 32 + quad * 8];
#pragma unroll
      for (int j = 0; j < 4; ++j)
        bfr[j] = *(const bf16x8*)&Bs1[(wn + j * 16 + lm) * 32 + quad * 8];
#pragma unroll
      for (int i = 0; i < 4; ++i)
#pragma unroll
        for (int j = 0; j < 4; ++j)
          acc[i][j] = __builtin_amdgcn_mfma_f32_16x16x32_bf16(af[i], bfr[j],
                                                              acc[i][j], 0, 0, 0);
    }
  }

  // C/D layout: col = lane&15, row = quad*4 + r (measured m89/m91)
  if (SPLIT3 && which == 2) {
    // transposed epilogue: store Vt[b][d][s] directly
    __syncthreads();
    bf16_t* myT = smem + wave * (16 * 68);
    const int b  = m0 >> mbShift;
    const int s0 = m0 & ((1 << mbShift) - 1);
    const int r8 = lane >> 3;
    const int c8 = lane & 7;
#pragma unroll
    for (int j = 0; j < 4; ++j) {
      const float bv = HAS_BIAS ? bias[n0 + wn + j * 16 + lm] : 0.f;
#pragma unroll
      for (int i = 0; i < 4; ++i)
#pragma unroll
        for (int r = 0; r < 4; ++r)
          myT[lm * 68 + i * 16 + quad * 4 + r] = (bf16_t)(acc[i][j][r] + bv);
      // per-wave region + in-order DS pipe: no barrier needed
#pragma unroll
      for (int t = 0; t < 2; ++t) {
        const int nr = t * 8 + r8;
        const bf16x8 vv = *(const bf16x8*)&myT[nr * 68 + c8 * 8];
        *(bf16x8*)&Cb[(long)b * sTv + (long)(n0 + wn + j * 16 + nr) * ldTv
                      + s0 + wm + c8 * 8] = vv;
      }
    }
  } else if (OUT_BF16) {
    __syncthreads();
    bf16_t* myEp = smem + wave * (16 * 68);
    const int r8 = lane >> 3;
    const int c8 = lane & 7;
    float cs[4] = {0.f, 0.f, 0.f, 0.f};
#pragma unroll
    for (int i = 0; i < 4; ++i) {
#pragma unroll
      for (int j = 0; j < 4; ++j) {
        const float bv = HAS_BIAS ? bias[n0 + wn + j * 16 + lm] : 0.f;
#pragma unroll
        for (int r = 0; r < 4; ++r) {
          float v = alpha * acc[i][j][r];
          if (EXP_COLSUM) { v = __expf(v); cs[j] += v; }
          v += bv;
          myEp[(quad * 4 + r) * 68 + j * 16 + lm] = (bf16_t)v;
        }
      }
#pragma unroll
      for (int t = 0; t < 2; ++t) {
        const int row = t * 8 + r8;
        const bf16x8 vv = *(const bf16x8*)&myEp[row * 68 + c8 * 8];
        *(bf16x8*)&Cb[bz * sC + (long)(m0 + wm + i * 16 + row) * ldC
                      + n0 + wn + c8 * 8] = vv;
      }
    }
    if (EXP_COLSUM) {
#pragma unroll
      for (int j = 0; j < 4; ++j) {
        float v = cs[j];
        v += __shfl_xor(v, 16);
        v += __shfl_xor(v, 32);
        if (quad == 0)
          atomicAdd(&L[bz * N + gn0 + wn + j * 16 + lm], v);
      }
    }
  } else {
    // fp32 out: full 64B lines already
#pragma unroll
    for (int j = 0; j < 4; ++j) {
      const int cn = n0 + wn + j * 16 + lm;
      const float bv = HAS_BIAS ? bias[n0 + wn + j * 16 + lm] : 0.f;
#pragma unroll
      for (int i = 0; i < 4; ++i) {
        const int rbase = m0 + wm + i * 16 + quad * 4;
#pragma unroll
        for (int r = 0; r < 4; ++r)
          Cf[bz * sC + (long)(rbase + r) * ldC + cn] = alpha * acc[i][j][r] + bv;
      }
    }
  }
}

// ---------------------------------------------------------------------------
// prep: one dispatch for (a) x fp32->bf16 (blocks 0..8191) and (b) the four
// 1024x1024 weight transposes (blocks 8192..12287).
// ---------------------------------------------------------------------------
__global__ __launch_bounds__(256)
void prep(const float* __restrict__ x, bf16_t* __restrict__ Xb,
          const float* __restrict__ w0, const float* __restrict__ w1,
          const float* __restrict__ w2, const float* __restrict__ w3,
          bf16_t* __restrict__ outQKV, bf16_t* __restrict__ outO)
{
  __shared__ float tile[32][33];
  const int id = blockIdx.x;
  if (id < 8192) {
    const long i = ((long)id * 256 + threadIdx.x) * 4;
    const float4 v = *(const float4*)(x + i);
    struct alignas(8) B4 { bf16_t a, b, c, d; };
    B4 o; o.a = (bf16_t)v.x; o.b = (bf16_t)v.y; o.c = (bf16_t)v.z; o.d = (bf16_t)v.w;
    *(B4*)(Xb + i) = o;
  } else {
    const int t = id - 8192;
    const int z = t >> 10;
    const int bx = t & 31, by = (t >> 5) & 31;
    const float* in = (z == 0) ? w0 : (z == 1) ? w1 : (z == 2) ? w2 : w3;
    bf16_t* out = (z < 3) ? outQKV + (long)z * 1024 * 1024 : outO;
    const int c0 = bx * 32, r0 = by * 32;
    const int tx = threadIdx.x & 31;
    const int ty = threadIdx.x >> 5;
#pragma unroll
    for (int i = 0; i < 32; i += 8)
      tile[ty + i][tx] = in[(long)(r0 + ty + i) * 1024 + (c0 + tx)];
    __syncthreads();
#pragma unroll
    for (int i = 0; i < 32; i += 8)
      out[(long)(c0 + ty + i) * 1024 + (r0 + tx)] = (bf16_t)tile[tx][ty + i];
  }
}

// Vt[b][d][s] *= 1/L[b][s]  (folds softmax denominator into V)
__global__ __launch_bounds__(256)
void scale_vt(bf16_t* __restrict__ Vt, const float* __restrict__ L, int S)
{
  const long base = ((long)blockIdx.x * blockDim.x + threadIdx.x) * 8;
  const int b  = (int)(base >> 21);
  const int s0 = (int)(base & (long)(S - 1));
  const float* Lb = L + b * S + s0;
  bf16x8 v = *(const bf16x8*)(Vt + base);
#pragma unroll
  for (int j = 0; j < 8; ++j)
    v[j] = (bf16_t)((float)v[j] / Lb[j]);
  *(bf16x8*)(Vt + base) = v;
}

// ---------------------------------------------------------------------------
extern "C" void kernel_launch(void* const* d_in, const int* in_sizes, int n_in,
                              void* d_out, int out_size, void* d_ws, size_t ws_size,
                              hipStream_t stream)
{
  const int Bz = 4, S = 2048, F = 1024, DK = 1024;
  const int M = Bz * S;

  const float* x  = (const float*)d_in[0];
  const float* Wq = (const float*)d_in[1];
  const float* bq = (const float*)d_in[2];
  const float* Wk = (const float*)d_in[3];
  const float* bk = (const float*)d_in[4];
  const float* Wv = (const float*)d_in[5];
  const float* bv = (const float*)d_in[6];
  const float* Wo = (const float*)d_in[7];
  const float* bo = (const float*)d_in[8];

  char* ws = (char*)d_ws;
  const size_t MB = 1ull << 20;
  bf16_t* Xb   = (bf16_t*)(ws + 0);        // dead after QKV gemm
  bf16_t* Sc   = (bf16_t*)(ws + 0);        // 32MB P (over dead Xb)
  bf16_t* Q    = (bf16_t*)(ws + 32 * MB);  // dead after scores gemm
  bf16_t* Ctx  = (bf16_t*)(ws + 32 * MB);
  bf16_t* Kb   = (bf16_t*)(ws + 48 * MB);
  bf16_t* Vt   = (bf16_t*)(ws + 64 * MB);  // written directly by QKV epilogue
  bf16_t* WcatT= (bf16_t*)(ws + 80 * MB);  // 6MB, dead after QKV
  float*  L    = (float*)(ws + 80 * MB);   // 32KB over dead WcatT
  bf16_t* WoT  = (bf16_t*)(ws + 86 * MB);  // 2MB

  const long coQ = 16 * MB;  // Q  at byte 32MB (bf16 elem offsets)
  const long coK = 24 * MB;  // Kb at byte 48MB
  const long coV = 32 * MB;  // Vt at byte 64MB (transposed store)

  prep<<<12288, 256, 0, stream>>>(x, Xb, Wq, Wk, Wv, Wo, WcatT, WoT);

  // merged Q/K/V projection; V chunk stored transposed as Vt[b][d][s]
  gemm_nt<1, 1, 0, 1><<<dim3(3 * DK / 128, M / 128, 1), 256, 0, stream>>>(
      Xb, WcatT, (void*)ws, bq, bk, bv, nullptr, M, 3 * DK, F, DK, 1.f,
      0, 0, 0, coQ, coK, coV, 11, S, (long)DK * S);

  // P[b][q][k] = exp(Q.K/sqrt(dk)); column sums -> L (fused, atomics)
  hipMemsetAsync(L, 0, (size_t)Bz * S * sizeof(float), stream);
  gemm_nt<1, 0, 1, 0><<<dim3(S / 128, S / 128, Bz), 256, 0, stream>>>(
      Q, Kb, Sc, nullptr, nullptr, nullptr, L, S, S, DK, S, 0.03125f,
      (long)S * DK, (long)S * DK, (long)S * S, 0, 0, 0, 0, 0, 0);

  scale_vt<<<((long)Bz * DK * S / 8) / 256, 256, 0, stream>>>(Vt, L, S);

  // ctx[b][q][d] = P[b] @ (V/L)[b]
  gemm_nt<1, 0, 0, 0><<<dim3(DK / 128, S / 128, Bz), 256, 0, stream>>>(
      Sc, Vt, Ctx, nullptr, nullptr, nullptr, nullptr, S, DK, S, DK, 1.f,
      (long)S * S, (long)S * DK, (long)S * DK, 0, 0, 0, 0, 0, 0);

  // out = ctx @ Wo + bo (fp32)
  gemm_nt<0, 1, 0, 0><<<dim3(F / 128, M / 128, 1), 256, 0, stream>>>(
      Ctx, WoT, d_out, bo, nullptr, nullptr, nullptr, M, F, DK, F, 1.f,
      0, 0, 0, 0, 0, 0, 0, 0, 0);
}